// Round 1
// baseline (532.343 us; speedup 1.0000x reference)
//
#include <hip/hip_runtime.h>

#define EF 16      // EDGE_FEAT
#define EH 32      // EDGE_HID
#define NF 128     // NODE_FEAT
#define K1 160     // EH + NF
#define HS 168     // LDS hA row stride (ushorts)
#define H2S 136    // LDS hB row stride (ushorts)

typedef __attribute__((ext_vector_type(8))) short bf16x8;
typedef __attribute__((ext_vector_type(4))) float f32x4;

__device__ __forceinline__ unsigned short f2b(float f) {  // fp32 -> bf16 RNE
  unsigned u = __float_as_uint(f);
  u += 0x7FFFu + ((u >> 16) & 1u);
  return (unsigned short)(u >> 16);
}

// ---------------- init: zero counts + build bf16-transposed weights ----------------
__global__ void k_init(unsigned* __restrict__ cnt, int n,
                       const float* __restrict__ W1, const float* __restrict__ W2,
                       unsigned short* __restrict__ w1t, unsigned short* __restrict__ w2t) {
  int i = blockIdx.x * blockDim.x + threadIdx.x;
  if (i < n) cnt[i] = 0u;
  if (i < K1 * NF) {                    // w1t[n][k] = W1[k][n]
    int nn = i / K1, k = i % K1;
    w1t[i] = f2b(W1[k * NF + nn]);
  } else if (i < K1 * NF + NF * NF) {   // w2t[n][k] = W2[k][n]
    int j = i - K1 * NF;
    int nn = j / NF, k = j % NF;
    w2t[j] = f2b(W2[k * NF + nn]);
  }
}

// pure histogram (rank array eliminated; slot assignment moved to k_perm's cursor)
__global__ void k_hist(const int* __restrict__ dst, unsigned* __restrict__ cnt, int n_edges) {
  int e = blockIdx.x * blockDim.x + threadIdx.x;
  if (e >= n_edges) return;
  atomicAdd(&cnt[dst[e]], 1u);
}

// block scans 1024 elems (256 thr x 4); exclusive partials + block sum
__global__ void k_scan1(const unsigned* __restrict__ cnt, unsigned* __restrict__ offs,
                        unsigned* __restrict__ bsum, int n) {
  __shared__ unsigned ts[256];
  int t = threadIdx.x;
  int base = blockIdx.x * 1024 + t * 4;
  unsigned v[4];
#pragma unroll
  for (int i = 0; i < 4; ++i) { int idx = base + i; v[i] = (idx < n) ? cnt[idx] : 0u; }
  unsigned run = 0;
#pragma unroll
  for (int i = 0; i < 4; ++i) { unsigned x = v[i]; v[i] = run; run += x; }
  ts[t] = run;
  __syncthreads();
  for (int off = 1; off < 256; off <<= 1) {
    unsigned add = (t >= off) ? ts[t - off] : 0u;
    __syncthreads();
    ts[t] += add;
    __syncthreads();
  }
  unsigned texcl = (t > 0) ? ts[t - 1] : 0u;
  if (t == 255) bsum[blockIdx.x] = ts[255];
#pragma unroll
  for (int i = 0; i < 4; ++i) { int idx = base + i; if (idx < n) offs[idx] = v[i] + texcl; }
}

// fused: each block redundantly scans bsum in LDS, then offsets its 1024 elems.
// also writes the cursor copy used for slot assignment in k_perm.
__global__ void k_scan3(unsigned* __restrict__ offs, unsigned* __restrict__ cursor,
                        const unsigned* __restrict__ bsum, int n, int nb) {
  __shared__ unsigned ts[256];
  int t = threadIdx.x;
  ts[t] = (t < nb) ? bsum[t] : 0u;
  __syncthreads();
  for (int off = 1; off < 256; off <<= 1) {
    unsigned add = (t >= off) ? ts[t - off] : 0u;
    __syncthreads();
    ts[t] += add;
    __syncthreads();
  }
  unsigned add = (blockIdx.x > 0) ? ts[blockIdx.x - 1] : 0u;
  int base = blockIdx.x * 1024 + t * 4;
#pragma unroll
  for (int i = 0; i < 4; ++i) {
    int idx = base + i;
    if (idx < n) { unsigned v = offs[idx] + add; offs[idx] = v; cursor[idx] = v; }
  }
}

// scatter ONLY an 8B (edge_id, ex) record. 12.8MB region fits aggregate L2 ->
// write-combining works, no partial-line amplification. No feature payload moved.
__global__ void k_perm(const int* __restrict__ dst, const float* __restrict__ logits,
                       unsigned* __restrict__ cursor, uint2* __restrict__ perm, int n_edges) {
  int e = blockIdx.x * blockDim.x + threadIdx.x;
  if (e >= n_edges) return;
  int d = dst[e];
  unsigned slot = atomicAdd(&cursor[d], 1u);
  float ex = __expf(logits[e]);   // no max-shift: logits ~N(0,1), fp32-safe
  perm[slot] = make_uint2((unsigned)e, __float_as_uint(ex));
}

// ---------------- per-node random-gather segmented sum + context (16->32 + ELU) ----
// one wave per node; 4 groups x 16 lanes. Group g handles records g, g+4, ...
// Each group's 16 lanes fetch one full 64B edge_feats row in a single transaction.
// fp32 accumulation throughout (better than the old bf16 prodb round-trip).
__global__ __launch_bounds__(256) void k_gather(
    const uint2* __restrict__ perm, const float* __restrict__ efeat,
    const unsigned* __restrict__ cnt, const unsigned* __restrict__ offs,
    const float* __restrict__ W_et, const float* __restrict__ b_et,
    unsigned short* __restrict__ ctxb, int n_nodes) {
  int node = (int)((blockIdx.x * blockDim.x + threadIdx.x) >> 6);
  if (node >= n_nodes) return;
  int lane = threadIdx.x & 63;
  unsigned start = offs[node];
  unsigned deg = cnt[node];
  int g = lane >> 4, c = lane & 15;
  float a = 0.0f, dsum = 0.0f;
  for (unsigned i = g; i < deg; i += 4) {
    uint2 rec = perm[start + i];               // 8B broadcast within group
    float ex = __uint_as_float(rec.y);
    float f = efeat[(size_t)rec.x * EF + c];   // 64B row, one transaction/group
    a += ex * f;
    dsum += ex;
  }
  // cross-group reduce: groups hold disjoint record subsets
  a += __shfl_xor(a, 16);      a += __shfl_xor(a, 32);
  dsum += __shfl_xor(dsum, 16); dsum += __shfl_xor(dsum, 32);
  float inv = (deg > 0) ? 1.0f / dsum : 0.0f;
  float S = (deg > 0) ? 1.0f : 0.0f;
  int j = lane & 31;
  float acc = 0.0f;
#pragma unroll
  for (int k = 0; k < 16; ++k) {
    float sk = __shfl(a, k);                   // feature-k sum lives in lane k
    acc += sk * W_et[k * EH + j];
  }
  float cv = acc * inv + S * b_et[j];
  float ctxv = (cv > 0.0f) ? cv : (__expf(cv) - 1.0f);
  if (lane < 32) ctxb[(size_t)node * EH + lane] = f2b(ctxv);
}

// ---------------- per-node 2-layer MLP via bf16 MFMA (unchanged) ----------------
// 64 nodes/block, 4 waves; wave w owns node rows [w*16, w*16+16), full 128 cols.
// A layout (m89): A[m=lane&15][k=(lane>>4)*8+j]; C/D: row=(lane>>4)*4+reg, col=lane&15.
__global__ __launch_bounds__(256) void k_node(
    const unsigned short* __restrict__ ctxb, const float* __restrict__ nf,
    const unsigned short* __restrict__ w1t, const unsigned short* __restrict__ w2t,
    const float* __restrict__ b1, const float* __restrict__ b2,
    float* __restrict__ out, int n_nodes) {
  __shared__ __align__(16) unsigned short hA[64 * HS];
  __shared__ __align__(16) unsigned short hB[64 * H2S];
  const int t = threadIdx.x;
  const int w = t >> 6, lane = t & 63;
  const int m = lane & 15, q = lane >> 4;
  int n0 = blockIdx.x * 64;
  if (n0 + 64 > n_nodes) n0 = n_nodes - 64;  // tail overlap: identical rewrites, benign

  // stage ctx (bf16 passthrough): 64x32, 8 ushorts/thread
  {
    int node = t >> 2, j = (t & 3) * 8;
    *(uint4*)&hA[node * HS + j] = *(const uint4*)&ctxb[(size_t)(n0 + node) * EH + j];
  }
  // stage node_feats fp32 -> bf16: 64x128, 8x float4/thread
#pragma unroll
  for (int i = 0; i < 8; ++i) {
    int idx = t + 256 * i;
    int node = idx >> 5, j = (idx & 31) * 4;
    float4 v = *(const float4*)&nf[(size_t)(n0 + node) * NF + j];
    unsigned short r[4] = {f2b(v.x), f2b(v.y), f2b(v.z), f2b(v.w)};
    *(uint2*)&hA[node * HS + EH + j] = *(const uint2*)r;
  }
  __syncthreads();

  const int mr = w * 16;
  f32x4 acc[8];
#pragma unroll
  for (int nt = 0; nt < 8; ++nt) acc[nt] = (f32x4){0.f, 0.f, 0.f, 0.f};
  for (int ks = 0; ks < 5; ++ks) {
    bf16x8 a = *(const bf16x8*)&hA[(mr + m) * HS + ks * 32 + q * 8];
#pragma unroll
    for (int nt = 0; nt < 8; ++nt) {
      bf16x8 b = *(const bf16x8*)&w1t[(size_t)(nt * 16 + m) * K1 + ks * 32 + q * 8];
      acc[nt] = __builtin_amdgcn_mfma_f32_16x16x32_bf16(a, b, acc[nt], 0, 0, 0);
    }
  }
  // epilogue 1: bias + relu -> hB (bf16), wave-private rows
#pragma unroll
  for (int nt = 0; nt < 8; ++nt) {
    float bb = b1[nt * 16 + m];
#pragma unroll
    for (int r = 0; r < 4; ++r) {
      float v = fmaxf(acc[nt][r] + bb, 0.0f);
      hB[(mr + q * 4 + r) * H2S + nt * 16 + m] = f2b(v);
    }
  }
  __syncthreads();

  f32x4 ac2[8];
#pragma unroll
  for (int nt = 0; nt < 8; ++nt) ac2[nt] = (f32x4){0.f, 0.f, 0.f, 0.f};
  for (int ks = 0; ks < 4; ++ks) {
    bf16x8 a = *(const bf16x8*)&hB[(mr + m) * H2S + ks * 32 + q * 8];
#pragma unroll
    for (int nt = 0; nt < 8; ++nt) {
      bf16x8 b = *(const bf16x8*)&w2t[(size_t)(nt * 16 + m) * NF + ks * 32 + q * 8];
      ac2[nt] = __builtin_amdgcn_mfma_f32_16x16x32_bf16(a, b, ac2[nt], 0, 0, 0);
    }
  }
#pragma unroll
  for (int nt = 0; nt < 8; ++nt) {
    float bb = b2[nt * 16 + m];
#pragma unroll
    for (int r = 0; r < 4; ++r) {
      out[(size_t)(n0 + mr + q * 4 + r) * NF + nt * 16 + m] = fmaxf(ac2[nt][r] + bb, 0.0f);
    }
  }
}

extern "C" void kernel_launch(void* const* d_in, const int* in_sizes, int n_in,
                              void* d_out, int out_size, void* d_ws, size_t ws_size,
                              hipStream_t stream) {
  const float* edge_logits = (const float*)d_in[0];
  const float* edge_feats  = (const float*)d_in[1];
  const float* node_feats  = (const float*)d_in[2];
  const int*   dst         = (const int*)d_in[3];
  const float* W_et        = (const float*)d_in[4];
  const float* b_et        = (const float*)d_in[5];
  const float* W1          = (const float*)d_in[6];
  const float* b1          = (const float*)d_in[7];
  const float* W2          = (const float*)d_in[8];
  const float* b2          = (const float*)d_in[9];
  float* out = (float*)d_out;

  const int E = in_sizes[0];          // 1,600,000
  const int n = in_sizes[2] / NF;     // 100,000

  // ws layout (u32 units)
  unsigned* cnt    = (unsigned*)d_ws;             // n
  unsigned* offs   = cnt + n;                     // n
  unsigned* cursor = offs + n;                    // n
  unsigned* bsum   = cursor + n;                  // 256
  uint2* perm = (uint2*)(((uintptr_t)(bsum + 256) + 7) & ~(uintptr_t)7);  // E x 8B
  unsigned short* ctxb = (unsigned short*)(perm + E);   // n*32 bf16
  unsigned short* w1t  = ctxb + (size_t)n * EH;   // 160*128 bf16
  unsigned short* w2t  = w1t + NF * K1;           // 128*128 bf16

  const int thr = 256;
  const int nscan = (n + 1023) / 1024;

  k_init<<<(n + thr - 1) / thr, thr, 0, stream>>>(cnt, n, W1, W2, w1t, w2t);
  k_hist<<<(E + thr - 1) / thr, thr, 0, stream>>>(dst, cnt, E);
  k_scan1<<<nscan, 256, 0, stream>>>(cnt, offs, bsum, n);
  k_scan3<<<nscan, 256, 0, stream>>>(offs, cursor, bsum, n, nscan);
  k_perm<<<(E + thr - 1) / thr, thr, 0, stream>>>(dst, edge_logits, cursor, perm, E);
  k_gather<<<(n * 64 + thr - 1) / thr, thr, 0, stream>>>(perm, edge_feats, cnt, offs,
                                                         W_et, b_et, ctxb, n);
  k_node<<<(n + 63) / 64, 256, 0, stream>>>(ctxb, node_feats, w1t, w2t, b1, b2, out, n);
}

// Round 2
// 470.701 us; speedup vs baseline: 1.1310x; 1.1310x over previous
//
#include <hip/hip_runtime.h>

#define EF 16      // EDGE_FEAT
#define EH 32      // EDGE_HID
#define NF 128     // NODE_FEAT
#define K1 160     // EH + NF
#define HS 168     // LDS hA row stride (ushorts)
#define H2S 136    // LDS hB row stride (ushorts)

typedef __attribute__((ext_vector_type(8))) short bf16x8;
typedef __attribute__((ext_vector_type(4))) float f32x4;

__device__ __forceinline__ unsigned short f2b(float f) {  // fp32 -> bf16 RNE
  unsigned u = __float_as_uint(f);
  u += 0x7FFFu + ((u >> 16) & 1u);
  return (unsigned short)(u >> 16);
}

// ---------------- init: zero counts + build bf16-transposed weights ----------------
__global__ void k_init(unsigned* __restrict__ cnt, int n,
                       const float* __restrict__ W1, const float* __restrict__ W2,
                       unsigned short* __restrict__ w1t, unsigned short* __restrict__ w2t) {
  int i = blockIdx.x * blockDim.x + threadIdx.x;
  if (i < n) cnt[i] = 0u;
  if (i < K1 * NF) {                    // w1t[n][k] = W1[k][n]
    int nn = i / K1, k = i % K1;
    w1t[i] = f2b(W1[k * NF + nn]);
  } else if (i < K1 * NF + NF * NF) {   // w2t[n][k] = W2[k][n]
    int j = i - K1 * NF;
    int nn = j / NF, k = j % NF;
    w2t[j] = f2b(W2[k * NF + nn]);
  }
}

// pure histogram
__global__ void k_hist(const int* __restrict__ dst, unsigned* __restrict__ cnt, int n_edges) {
  int e = blockIdx.x * blockDim.x + threadIdx.x;
  if (e >= n_edges) return;
  atomicAdd(&cnt[dst[e]], 1u);
}

// block scans 1024 elems (256 thr x 4); exclusive partials + block sum
__global__ void k_scan1(const unsigned* __restrict__ cnt, unsigned* __restrict__ offs,
                        unsigned* __restrict__ bsum, int n) {
  __shared__ unsigned ts[256];
  int t = threadIdx.x;
  int base = blockIdx.x * 1024 + t * 4;
  unsigned v[4];
#pragma unroll
  for (int i = 0; i < 4; ++i) { int idx = base + i; v[i] = (idx < n) ? cnt[idx] : 0u; }
  unsigned run = 0;
#pragma unroll
  for (int i = 0; i < 4; ++i) { unsigned x = v[i]; v[i] = run; run += x; }
  ts[t] = run;
  __syncthreads();
  for (int off = 1; off < 256; off <<= 1) {
    unsigned add = (t >= off) ? ts[t - off] : 0u;
    __syncthreads();
    ts[t] += add;
    __syncthreads();
  }
  unsigned texcl = (t > 0) ? ts[t - 1] : 0u;
  if (t == 255) bsum[blockIdx.x] = ts[255];
#pragma unroll
  for (int i = 0; i < 4; ++i) { int idx = base + i; if (idx < n) offs[idx] = v[i] + texcl; }
}

// fused: each block redundantly scans bsum in LDS, then offsets its 1024 elems.
// also writes the cursor copy used for slot assignment in k_perm.
__global__ void k_scan3(unsigned* __restrict__ offs, unsigned* __restrict__ cursor,
                        const unsigned* __restrict__ bsum, int n, int nb) {
  __shared__ unsigned ts[256];
  int t = threadIdx.x;
  ts[t] = (t < nb) ? bsum[t] : 0u;
  __syncthreads();
  for (int off = 1; off < 256; off <<= 1) {
    unsigned add = (t >= off) ? ts[t - off] : 0u;
    __syncthreads();
    ts[t] += add;
    __syncthreads();
  }
  unsigned add = (blockIdx.x > 0) ? ts[blockIdx.x - 1] : 0u;
  int base = blockIdx.x * 1024 + t * 4;
#pragma unroll
  for (int i = 0; i < 4; ++i) {
    int idx = base + i;
    if (idx < n) { unsigned v = offs[idx] + add; offs[idx] = v; cursor[idx] = v; }
  }
}

// XCD-partitioned permutation build. blockIdx = chunk*8 + xcdSlot; block filters
// edges to its XCD's exclusive node range, so each node's 128B record line is
// written (and its cursor atomically bumped) by ONE XCD only -> lines stay dirty-
// resident in that XCD's L2 until fully populated -> full-line writebacks.
// dst/logits reads are nontemporal so streaming doesn't evict the dirty perm lines.
// If the blockIdx%8 -> XCD mapping ever changes this only loses speed, not
// correctness (every edge is still processed exactly once).
__global__ __launch_bounds__(256) void k_perm(
    const int* __restrict__ dst, const float* __restrict__ logits,
    unsigned* __restrict__ cursor, uint2* __restrict__ perm,
    int n_edges, int n_nodes, int chunks) {
  int xcd = blockIdx.x & 7;
  int chunk = blockIdx.x >> 3;
  int lo = (int)((long long)n_nodes * xcd >> 3);
  int hi = (int)((long long)n_nodes * (xcd + 1) >> 3);
  int per = (n_edges + chunks - 1) / chunks;
  int e0 = chunk * per;
  int e1 = min(e0 + per, n_edges);
  for (int e = e0 + (int)threadIdx.x; e < e1; e += 256) {
    int d = __builtin_nontemporal_load(&dst[e]);
    if (d >= lo && d < hi) {
      unsigned slot = atomicAdd(&cursor[d], 1u);
      float ex = __expf(__builtin_nontemporal_load(&logits[e]));
      perm[slot] = make_uint2((unsigned)e, __float_as_uint(ex));
    }
  }
}

// ---------------- per-node random-gather segmented sum + context (16->32 + ELU) ----
// one wave per node; 4 groups x 16 lanes. Group g handles records g, g+4, ...
// Each group's 16 lanes fetch one full 64B edge_feats row in a single transaction.
__global__ __launch_bounds__(256) void k_gather(
    const uint2* __restrict__ perm, const float* __restrict__ efeat,
    const unsigned* __restrict__ cnt, const unsigned* __restrict__ offs,
    const float* __restrict__ W_et, const float* __restrict__ b_et,
    unsigned short* __restrict__ ctxb, int n_nodes) {
  int node = (int)((blockIdx.x * blockDim.x + threadIdx.x) >> 6);
  if (node >= n_nodes) return;
  int lane = threadIdx.x & 63;
  unsigned start = offs[node];
  unsigned deg = cnt[node];
  int g = lane >> 4, c = lane & 15;
  float a = 0.0f, dsum = 0.0f;
  for (unsigned i = g; i < deg; i += 4) {
    uint2 rec = perm[start + i];               // 8B broadcast within group
    float ex = __uint_as_float(rec.y);
    float f = efeat[(size_t)rec.x * EF + c];   // 64B row, one transaction/group
    a += ex * f;
    dsum += ex;
  }
  // cross-group reduce: groups hold disjoint record subsets
  a += __shfl_xor(a, 16);      a += __shfl_xor(a, 32);
  dsum += __shfl_xor(dsum, 16); dsum += __shfl_xor(dsum, 32);
  float inv = (deg > 0) ? 1.0f / dsum : 0.0f;
  float S = (deg > 0) ? 1.0f : 0.0f;
  int j = lane & 31;
  float acc = 0.0f;
#pragma unroll
  for (int k = 0; k < 16; ++k) {
    float sk = __shfl(a, k);                   // feature-k sum lives in lane k
    acc += sk * W_et[k * EH + j];
  }
  float cv = acc * inv + S * b_et[j];
  float ctxv = (cv > 0.0f) ? cv : (__expf(cv) - 1.0f);
  if (lane < 32) ctxb[(size_t)node * EH + lane] = f2b(ctxv);
}

// ---------------- per-node 2-layer MLP via bf16 MFMA (unchanged) ----------------
// 64 nodes/block, 4 waves; wave w owns node rows [w*16, w*16+16), full 128 cols.
// A layout (m89): A[m=lane&15][k=(lane>>4)*8+j]; C/D: row=(lane>>4)*4+reg, col=lane&15.
__global__ __launch_bounds__(256) void k_node(
    const unsigned short* __restrict__ ctxb, const float* __restrict__ nf,
    const unsigned short* __restrict__ w1t, const unsigned short* __restrict__ w2t,
    const float* __restrict__ b1, const float* __restrict__ b2,
    float* __restrict__ out, int n_nodes) {
  __shared__ __align__(16) unsigned short hA[64 * HS];
  __shared__ __align__(16) unsigned short hB[64 * H2S];
  const int t = threadIdx.x;
  const int w = t >> 6, lane = t & 63;
  const int m = lane & 15, q = lane >> 4;
  int n0 = blockIdx.x * 64;
  if (n0 + 64 > n_nodes) n0 = n_nodes - 64;  // tail overlap: identical rewrites, benign

  // stage ctx (bf16 passthrough): 64x32, 8 ushorts/thread
  {
    int node = t >> 2, j = (t & 3) * 8;
    *(uint4*)&hA[node * HS + j] = *(const uint4*)&ctxb[(size_t)(n0 + node) * EH + j];
  }
  // stage node_feats fp32 -> bf16: 64x128, 8x float4/thread
#pragma unroll
  for (int i = 0; i < 8; ++i) {
    int idx = t + 256 * i;
    int node = idx >> 5, j = (idx & 31) * 4;
    float4 v = *(const float4*)&nf[(size_t)(n0 + node) * NF + j];
    unsigned short r[4] = {f2b(v.x), f2b(v.y), f2b(v.z), f2b(v.w)};
    *(uint2*)&hA[node * HS + EH + j] = *(const uint2*)r;
  }
  __syncthreads();

  const int mr = w * 16;
  f32x4 acc[8];
#pragma unroll
  for (int nt = 0; nt < 8; ++nt) acc[nt] = (f32x4){0.f, 0.f, 0.f, 0.f};
  for (int ks = 0; ks < 5; ++ks) {
    bf16x8 a = *(const bf16x8*)&hA[(mr + m) * HS + ks * 32 + q * 8];
#pragma unroll
    for (int nt = 0; nt < 8; ++nt) {
      bf16x8 b = *(const bf16x8*)&w1t[(size_t)(nt * 16 + m) * K1 + ks * 32 + q * 8];
      acc[nt] = __builtin_amdgcn_mfma_f32_16x16x32_bf16(a, b, acc[nt], 0, 0, 0);
    }
  }
  // epilogue 1: bias + relu -> hB (bf16), wave-private rows
#pragma unroll
  for (int nt = 0; nt < 8; ++nt) {
    float bb = b1[nt * 16 + m];
#pragma unroll
    for (int r = 0; r < 4; ++r) {
      float v = fmaxf(acc[nt][r] + bb, 0.0f);
      hB[(mr + q * 4 + r) * H2S + nt * 16 + m] = f2b(v);
    }
  }
  __syncthreads();

  f32x4 ac2[8];
#pragma unroll
  for (int nt = 0; nt < 8; ++nt) ac2[nt] = (f32x4){0.f, 0.f, 0.f, 0.f};
  for (int ks = 0; ks < 4; ++ks) {
    bf16x8 a = *(const bf16x8*)&hB[(mr + m) * H2S + ks * 32 + q * 8];
#pragma unroll
    for (int nt = 0; nt < 8; ++nt) {
      bf16x8 b = *(const bf16x8*)&w2t[(size_t)(nt * 16 + m) * NF + ks * 32 + q * 8];
      ac2[nt] = __builtin_amdgcn_mfma_f32_16x16x32_bf16(a, b, ac2[nt], 0, 0, 0);
    }
  }
#pragma unroll
  for (int nt = 0; nt < 8; ++nt) {
    float bb = b2[nt * 16 + m];
#pragma unroll
    for (int r = 0; r < 4; ++r) {
      out[(size_t)(n0 + mr + q * 4 + r) * NF + nt * 16 + m] = fmaxf(ac2[nt][r] + bb, 0.0f);
    }
  }
}

extern "C" void kernel_launch(void* const* d_in, const int* in_sizes, int n_in,
                              void* d_out, int out_size, void* d_ws, size_t ws_size,
                              hipStream_t stream) {
  const float* edge_logits = (const float*)d_in[0];
  const float* edge_feats  = (const float*)d_in[1];
  const float* node_feats  = (const float*)d_in[2];
  const int*   dst         = (const int*)d_in[3];
  const float* W_et        = (const float*)d_in[4];
  const float* b_et        = (const float*)d_in[5];
  const float* W1          = (const float*)d_in[6];
  const float* b1          = (const float*)d_in[7];
  const float* W2          = (const float*)d_in[8];
  const float* b2          = (const float*)d_in[9];
  float* out = (float*)d_out;

  const int E = in_sizes[0];          // 1,600,000
  const int n = in_sizes[2] / NF;     // 100,000

  // ws layout (u32 units)
  unsigned* cnt    = (unsigned*)d_ws;             // n
  unsigned* offs   = cnt + n;                     // n
  unsigned* cursor = offs + n;                    // n
  unsigned* bsum   = cursor + n;                  // 256
  uint2* perm = (uint2*)(((uintptr_t)(bsum + 256) + 255) & ~(uintptr_t)255);  // E x 8B, line-aligned
  unsigned short* ctxb = (unsigned short*)(perm + E);   // n*32 bf16
  unsigned short* w1t  = ctxb + (size_t)n * EH;   // 160*128 bf16
  unsigned short* w2t  = w1t + NF * K1;           // 128*128 bf16

  const int thr = 256;
  const int nscan = (n + 1023) / 1024;
  const int chunks = 256;             // k_perm grid = chunks * 8 XCD slots

  k_init<<<(n + thr - 1) / thr, thr, 0, stream>>>(cnt, n, W1, W2, w1t, w2t);
  k_hist<<<(E + thr - 1) / thr, thr, 0, stream>>>(dst, cnt, E);
  k_scan1<<<nscan, 256, 0, stream>>>(cnt, offs, bsum, n);
  k_scan3<<<nscan, 256, 0, stream>>>(offs, cursor, bsum, n, nscan);
  k_perm<<<chunks * 8, 256, 0, stream>>>(dst, edge_logits, cursor, perm, E, n, chunks);
  k_gather<<<(n * 64 + thr - 1) / thr, thr, 0, stream>>>(perm, edge_feats, cnt, offs,
                                                         W_et, b_et, ctxb, n);
  k_node<<<(n + 63) / 64, 256, 0, stream>>>(ctxb, node_feats, w1t, w2t, b1, b2, out, n);
}

// Round 3
// 430.592 us; speedup vs baseline: 1.2363x; 1.0931x over previous
//
#include <hip/hip_runtime.h>

#define EF 16      // EDGE_FEAT
#define EH 32      // EDGE_HID
#define NF 128     // NODE_FEAT
#define K1 160     // EH + NF
#define HS 168     // LDS hA row stride (ushorts)
#define H2S 136    // LDS hB row stride (ushorts)

typedef __attribute__((ext_vector_type(8))) short bf16x8;
typedef __attribute__((ext_vector_type(4))) float f32x4;

__device__ __forceinline__ unsigned short f2b(float f) {  // fp32 -> bf16 RNE
  unsigned u = __float_as_uint(f);
  u += 0x7FFFu + ((u >> 16) & 1u);
  return (unsigned short)(u >> 16);
}

// ---------------- init: zero counts + build bf16-transposed weights ----------------
__global__ void k_init(unsigned* __restrict__ cnt, int n,
                       const float* __restrict__ W1, const float* __restrict__ W2,
                       unsigned short* __restrict__ w1t, unsigned short* __restrict__ w2t) {
  int i = blockIdx.x * blockDim.x + threadIdx.x;
  if (i < n) cnt[i] = 0u;
  if (i < K1 * NF) {                    // w1t[n][k] = W1[k][n]
    int nn = i / K1, k = i % K1;
    w1t[i] = f2b(W1[k * NF + nn]);
  } else if (i < K1 * NF + NF * NF) {   // w2t[n][k] = W2[k][n]
    int j = i - K1 * NF;
    int nn = j / NF, k = j % NF;
    w2t[j] = f2b(W2[k * NF + nn]);
  }
}

// histogram; atomic return value doubles as the edge's within-node rank
// (pays the 1.6M-atomic cost ONCE; k_perm then needs no atomics at all)
__global__ void k_hist(const int* __restrict__ dst, unsigned* __restrict__ cnt,
                       unsigned* __restrict__ rank, int n_edges) {
  int e = blockIdx.x * blockDim.x + threadIdx.x;
  if (e >= n_edges) return;
  rank[e] = atomicAdd(&cnt[dst[e]], 1u);
}

// block scans 1024 elems (256 thr x 4); exclusive partials + block sum
__global__ void k_scan1(const unsigned* __restrict__ cnt, unsigned* __restrict__ offs,
                        unsigned* __restrict__ bsum, int n) {
  __shared__ unsigned ts[256];
  int t = threadIdx.x;
  int base = blockIdx.x * 1024 + t * 4;
  unsigned v[4];
#pragma unroll
  for (int i = 0; i < 4; ++i) { int idx = base + i; v[i] = (idx < n) ? cnt[idx] : 0u; }
  unsigned run = 0;
#pragma unroll
  for (int i = 0; i < 4; ++i) { unsigned x = v[i]; v[i] = run; run += x; }
  ts[t] = run;
  __syncthreads();
  for (int off = 1; off < 256; off <<= 1) {
    unsigned add = (t >= off) ? ts[t - off] : 0u;
    __syncthreads();
    ts[t] += add;
    __syncthreads();
  }
  unsigned texcl = (t > 0) ? ts[t - 1] : 0u;
  if (t == 255) bsum[blockIdx.x] = ts[255];
#pragma unroll
  for (int i = 0; i < 4; ++i) { int idx = base + i; if (idx < n) offs[idx] = v[i] + texcl; }
}

// fused: each block redundantly scans bsum in LDS, then offsets its 1024 elems
__global__ void k_scan3(unsigned* __restrict__ offs, const unsigned* __restrict__ bsum,
                        int n, int nb) {
  __shared__ unsigned ts[256];
  int t = threadIdx.x;
  ts[t] = (t < nb) ? bsum[t] : 0u;
  __syncthreads();
  for (int off = 1; off < 256; off <<= 1) {
    unsigned add = (t >= off) ? ts[t - off] : 0u;
    __syncthreads();
    ts[t] += add;
    __syncthreads();
  }
  unsigned add = (blockIdx.x > 0) ? ts[blockIdx.x - 1] : 0u;
  int base = blockIdx.x * 1024 + t * 4;
#pragma unroll
  for (int i = 0; i < 4; ++i) { int idx = base + i; if (idx < n) offs[idx] += add; }
}

// XCD-partitioned, ATOMIC-FREE permutation build. blockIdx = chunk*8 + xcdSlot;
// block filters edges to its XCD's exclusive node range so each node's 128B perm
// line is written by ONE XCD only (dirty-resident in that L2 until full).
// slot = offs[d] + rank[d] is globally collision-free (rank from k_hist).
// dst/rank/logits re-reads across the 8 sweeps are absorbed by the shared 256MB L3
// (cached loads on purpose - round 2's nontemporal dst defeated that).
__global__ __launch_bounds__(256) void k_perm(
    const int* __restrict__ dst, const unsigned* __restrict__ rank,
    const float* __restrict__ logits, const unsigned* __restrict__ offs,
    uint2* __restrict__ perm, int n_edges, int nps, int n_nodes, int chunks) {
  int xcd = blockIdx.x & 7;
  int chunk = blockIdx.x >> 3;
  int lo = xcd * nps;
  int hi = min(lo + nps, n_nodes);
  int per = (n_edges + chunks - 1) / chunks;
  int e0 = chunk * per;
  int e1 = min(e0 + per, n_edges);
  for (int e = e0 + (int)threadIdx.x; e < e1; e += 256) {
    int d = dst[e];
    if (d >= lo && d < hi) {
      unsigned slot = offs[d] + rank[e];
      float ex = __expf(logits[e]);   // no max-shift: logits ~N(0,1), fp32-safe
      perm[slot] = make_uint2((unsigned)e, __float_as_uint(ex));
    }
  }
}

// ---------------- per-node random-gather segmented sum + context (16->32 + ELU) ----
// one wave per node; 4 groups x 16 lanes; group g owns records g, g+4, g+8, ...
// MAIN LOOP UNROLLED 4x: 4 independent efeat HBM fetches in flight per lane
// (the round-2 version had 1 -> latency-bound at 14% BW).
// Node mapping is XCD-swizzled to match k_perm's partition, so perm reads hit
// the dirty lines still resident in this XCD's L2.
__global__ __launch_bounds__(256) void k_gather(
    const uint2* __restrict__ perm, const float* __restrict__ efeat,
    const unsigned* __restrict__ cnt, const unsigned* __restrict__ offs,
    const float* __restrict__ W_et, const float* __restrict__ b_et,
    unsigned short* __restrict__ ctxb, int nps, int n_nodes) {
  int slot4 = blockIdx.x & 7;
  int idx = blockIdx.x >> 3;
  int node = slot4 * nps + (idx << 2) + (int)(threadIdx.x >> 6);
  int slot_end = min(slot4 * nps + nps, n_nodes);
  if (node >= slot_end) return;
  int lane = threadIdx.x & 63;
  unsigned start = offs[node];
  unsigned deg = cnt[node];
  int g = lane >> 4, c = lane & 15;
  float a = 0.0f, dsum = 0.0f;
  unsigned i = g;
  for (; i + 12 < deg; i += 16) {        // 4 records per group per pass
    uint2 r0 = perm[start + i];
    uint2 r1 = perm[start + i + 4];
    uint2 r2 = perm[start + i + 8];
    uint2 r3 = perm[start + i + 12];
    float f0 = __builtin_nontemporal_load(&efeat[(size_t)r0.x * EF + c]);
    float f1 = __builtin_nontemporal_load(&efeat[(size_t)r1.x * EF + c]);
    float f2 = __builtin_nontemporal_load(&efeat[(size_t)r2.x * EF + c]);
    float f3 = __builtin_nontemporal_load(&efeat[(size_t)r3.x * EF + c]);
    float e0 = __uint_as_float(r0.y), e1 = __uint_as_float(r1.y);
    float e2 = __uint_as_float(r2.y), e3 = __uint_as_float(r3.y);
    a += e0 * f0 + e1 * f1 + e2 * f2 + e3 * f3;
    dsum += (e0 + e1) + (e2 + e3);
  }
  for (; i < deg; i += 4) {              // tail
    uint2 rec = perm[start + i];
    float ex = __uint_as_float(rec.y);
    float f = __builtin_nontemporal_load(&efeat[(size_t)rec.x * EF + c]);
    a += ex * f;
    dsum += ex;
  }
  // cross-group reduce: groups hold disjoint record subsets
  a += __shfl_xor(a, 16);      a += __shfl_xor(a, 32);
  dsum += __shfl_xor(dsum, 16); dsum += __shfl_xor(dsum, 32);
  float inv = (deg > 0) ? 1.0f / dsum : 0.0f;
  float S = (deg > 0) ? 1.0f : 0.0f;
  int j = lane & 31;
  float acc = 0.0f;
#pragma unroll
  for (int k = 0; k < 16; ++k) {
    float sk = __shfl(a, k);             // feature-k sum lives in lane k
    acc += sk * W_et[k * EH + j];
  }
  float cv = acc * inv + S * b_et[j];
  float ctxv = (cv > 0.0f) ? cv : (__expf(cv) - 1.0f);
  if (lane < 32) ctxb[(size_t)node * EH + lane] = f2b(ctxv);
}

// ---------------- per-node 2-layer MLP via bf16 MFMA (unchanged) ----------------
// 64 nodes/block, 4 waves; wave w owns node rows [w*16, w*16+16), full 128 cols.
// A layout (m89): A[m=lane&15][k=(lane>>4)*8+j]; C/D: row=(lane>>4)*4+reg, col=lane&15.
__global__ __launch_bounds__(256) void k_node(
    const unsigned short* __restrict__ ctxb, const float* __restrict__ nf,
    const unsigned short* __restrict__ w1t, const unsigned short* __restrict__ w2t,
    const float* __restrict__ b1, const float* __restrict__ b2,
    float* __restrict__ out, int n_nodes) {
  __shared__ __align__(16) unsigned short hA[64 * HS];
  __shared__ __align__(16) unsigned short hB[64 * H2S];
  const int t = threadIdx.x;
  const int w = t >> 6, lane = t & 63;
  const int m = lane & 15, q = lane >> 4;
  int n0 = blockIdx.x * 64;
  if (n0 + 64 > n_nodes) n0 = n_nodes - 64;  // tail overlap: identical rewrites, benign

  // stage ctx (bf16 passthrough): 64x32, 8 ushorts/thread
  {
    int node = t >> 2, j = (t & 3) * 8;
    *(uint4*)&hA[node * HS + j] = *(const uint4*)&ctxb[(size_t)(n0 + node) * EH + j];
  }
  // stage node_feats fp32 -> bf16: 64x128, 8x float4/thread
#pragma unroll
  for (int i = 0; i < 8; ++i) {
    int idx = t + 256 * i;
    int node = idx >> 5, j = (idx & 31) * 4;
    float4 v = *(const float4*)&nf[(size_t)(n0 + node) * NF + j];
    unsigned short r[4] = {f2b(v.x), f2b(v.y), f2b(v.z), f2b(v.w)};
    *(uint2*)&hA[node * HS + EH + j] = *(const uint2*)r;
  }
  __syncthreads();

  const int mr = w * 16;
  f32x4 acc[8];
#pragma unroll
  for (int nt = 0; nt < 8; ++nt) acc[nt] = (f32x4){0.f, 0.f, 0.f, 0.f};
  for (int ks = 0; ks < 5; ++ks) {
    bf16x8 a = *(const bf16x8*)&hA[(mr + m) * HS + ks * 32 + q * 8];
#pragma unroll
    for (int nt = 0; nt < 8; ++nt) {
      bf16x8 b = *(const bf16x8*)&w1t[(size_t)(nt * 16 + m) * K1 + ks * 32 + q * 8];
      acc[nt] = __builtin_amdgcn_mfma_f32_16x16x32_bf16(a, b, acc[nt], 0, 0, 0);
    }
  }
  // epilogue 1: bias + relu -> hB (bf16), wave-private rows
#pragma unroll
  for (int nt = 0; nt < 8; ++nt) {
    float bb = b1[nt * 16 + m];
#pragma unroll
    for (int r = 0; r < 4; ++r) {
      float v = fmaxf(acc[nt][r] + bb, 0.0f);
      hB[(mr + q * 4 + r) * H2S + nt * 16 + m] = f2b(v);
    }
  }
  __syncthreads();

  f32x4 ac2[8];
#pragma unroll
  for (int nt = 0; nt < 8; ++nt) ac2[nt] = (f32x4){0.f, 0.f, 0.f, 0.f};
  for (int ks = 0; ks < 4; ++ks) {
    bf16x8 a = *(const bf16x8*)&hB[(mr + m) * H2S + ks * 32 + q * 8];
#pragma unroll
    for (int nt = 0; nt < 8; ++nt) {
      bf16x8 b = *(const bf16x8*)&w2t[(size_t)(nt * 16 + m) * NF + ks * 32 + q * 8];
      ac2[nt] = __builtin_amdgcn_mfma_f32_16x16x32_bf16(a, b, ac2[nt], 0, 0, 0);
    }
  }
#pragma unroll
  for (int nt = 0; nt < 8; ++nt) {
    float bb = b2[nt * 16 + m];
#pragma unroll
    for (int r = 0; r < 4; ++r) {
      out[(size_t)(n0 + mr + q * 4 + r) * NF + nt * 16 + m] = fmaxf(ac2[nt][r] + bb, 0.0f);
    }
  }
}

extern "C" void kernel_launch(void* const* d_in, const int* in_sizes, int n_in,
                              void* d_out, int out_size, void* d_ws, size_t ws_size,
                              hipStream_t stream) {
  const float* edge_logits = (const float*)d_in[0];
  const float* edge_feats  = (const float*)d_in[1];
  const float* node_feats  = (const float*)d_in[2];
  const int*   dst         = (const int*)d_in[3];
  const float* W_et        = (const float*)d_in[4];
  const float* b_et        = (const float*)d_in[5];
  const float* W1          = (const float*)d_in[6];
  const float* b1          = (const float*)d_in[7];
  const float* W2          = (const float*)d_in[8];
  const float* b2          = (const float*)d_in[9];
  float* out = (float*)d_out;

  const int E = in_sizes[0];          // 1,600,000
  const int n = in_sizes[2] / NF;     // 100,000

  // ws layout (u32 units)
  unsigned* cnt  = (unsigned*)d_ws;               // n
  unsigned* offs = cnt + n;                       // n
  unsigned* bsum = offs + n;                      // 256
  unsigned* rank = bsum + 256;                    // E
  uint2* perm = (uint2*)(((uintptr_t)(rank + E) + 255) & ~(uintptr_t)255);  // E x 8B, line-aligned
  unsigned short* ctxb = (unsigned short*)(perm + E);   // n*32 bf16
  unsigned short* w1t  = ctxb + (size_t)n * EH;   // 160*128 bf16
  unsigned short* w2t  = w1t + NF * K1;           // 128*128 bf16

  const int thr = 256;
  const int nscan = (n + 1023) / 1024;
  const int chunks = 256;             // k_perm grid = chunks * 8 XCD slots
  const int nps = (n + 7) >> 3;       // nodes per XCD slice (shared by k_perm/k_gather)

  k_init<<<(n + thr - 1) / thr, thr, 0, stream>>>(cnt, n, W1, W2, w1t, w2t);
  k_hist<<<(E + thr - 1) / thr, thr, 0, stream>>>(dst, cnt, rank, E);
  k_scan1<<<nscan, 256, 0, stream>>>(cnt, offs, bsum, n);
  k_scan3<<<nscan, 256, 0, stream>>>(offs, bsum, n, nscan);
  k_perm<<<chunks * 8, 256, 0, stream>>>(dst, rank, edge_logits, offs, perm, E, nps, n, chunks);
  const int gblocks = 8 * ((nps + 3) >> 2);   // 4 nodes (waves) per block, XCD-sliced
  k_gather<<<gblocks, 256, 0, stream>>>(perm, edge_feats, cnt, offs, W_et, b_et, ctxb, nps, n);
  k_node<<<(n + 63) / 64, 256, 0, stream>>>(ctxb, node_feats, w1t, w2t, b1, b2, out, n);
}